// Round 3
// baseline (472.163 us; speedup 1.0000x reference)
//
#include <hip/hip_runtime.h>
#include <hip/hip_bf16.h>

#define CM 256
#define CZ 128
#define CH 32
#define SS 128
#define NN 384

typedef short bf16x8 __attribute__((ext_vector_type(8)));
typedef float f32x4 __attribute__((ext_vector_type(4)));
typedef unsigned short us4 __attribute__((ext_vector_type(4)));
typedef unsigned short us8 __attribute__((ext_vector_type(8)));

__device__ __forceinline__ unsigned short f2bf(float f) {
    __hip_bfloat16 h = __float2bfloat16(f);
    return __builtin_bit_cast(unsigned short, h);
}

// ---------------- K0: weight prep ----------------
// WoF: fragment-linear Wo for k2 phase-2 direct loads:
//   WoF[(((cch*8)+zb)*64 + l)*8 + e] = Wo[(cch*32 + (l>>4)*8 + e)][zb*16 + (l&15)]
// WT = [WlT(32x256) | WrT(32x256)]
__global__ __launch_bounds__(256) void k0_transpose(
    const float* __restrict__ Wo, const float* __restrict__ Wl, const float* __restrict__ Wr,
    unsigned short* __restrict__ WoF, unsigned short* __restrict__ WT) {
    int n = blockIdx.x;  // 0..127
    int base = n * 1024;
#pragma unroll
    for (int u = 0; u < 4; u++) {
        int w   = base + u * 256 + threadIdx.x;   // 0..131071
        int e   = w & 7;
        int l   = (w >> 3) & 63;
        int zb  = (w >> 9) & 7;
        int cch = w >> 12;
        WoF[w] = f2bf(Wo[(size_t)(cch * 32 + (l >> 4) * 8 + e) * CZ + zb * 16 + (l & 15)]);
    }
    int k = threadIdx.x;  // blockDim == 256 == CM
    if (n < 32) {
        WT[n * CM + k] = f2bf(Wl[(size_t)k * CH + n]);
    } else if (n < 64) {
        WT[32 * CM + (n - 32) * CM + k] = f2bf(Wr[(size_t)k * CH + (n - 32)]);
    }
}

// ---------------- K1: LayerNorm + projections. Block = (i, s-half of 64). 256 thr, 2 blocks/CU ----------------
__global__ __launch_bounds__(256, 2) void k1_ln_proj(
    const float* __restrict__ msa, const float* __restrict__ g, const float* __restrict__ bta,
    const unsigned short* __restrict__ WT, const float* __restrict__ bl, const float* __restrict__ br,
    unsigned short* __restrict__ Lt, unsigned short* __restrict__ Rt)
{
    __shared__ unsigned short A_lds[64 * 264];
    __shared__ unsigned short B_lds[64 * 264];

    const int i    = blockIdx.x;
    const int sh   = blockIdx.y;
    const int t    = threadIdx.x;
    const int wv   = t >> 6;
    const int lane = t & 63;
    const int lr   = lane & 15, lg = lane >> 4;

    const float4 gv = ((const float4*)g)[lane];
    const float4 bv = ((const float4*)bta)[lane];
#pragma unroll 8
    for (int r = 0; r < 16; r++) {
        int sl = wv * 16 + r;
        int s  = sh * 64 + sl;
        float4 v = ((const float4*)(msa + ((size_t)s * NN + i) * CM))[lane];
        float sum = v.x + v.y + v.z + v.w;
        float sq  = v.x * v.x + v.y * v.y + v.z * v.z + v.w * v.w;
#pragma unroll
        for (int off = 32; off >= 1; off >>= 1) {
            sum += __shfl_xor(sum, off, 64);
            sq  += __shfl_xor(sq, off, 64);
        }
        float mu = sum * (1.f / CM);
        float rs = rsqrtf(sq * (1.f / CM) - mu * mu + 1e-5f);
        us4 pk;
        pk[0] = f2bf((v.x - mu) * rs * gv.x + bv.x);
        pk[1] = f2bf((v.y - mu) * rs * gv.y + bv.y);
        pk[2] = f2bf((v.z - mu) * rs * gv.z + bv.z);
        pk[3] = f2bf((v.w - mu) * rs * gv.w + bv.w);
        *(us4*)&A_lds[sl * 264 + lane * 4] = pk;
    }
#pragma unroll
    for (int u = 0; u < 8; u++) {
        int id = u * 256 + t;
        *(us8*)&B_lds[(id >> 5) * 264 + (id & 31) * 8] = *(const us8*)&WT[id * 8];
    }
    __syncthreads();

    const int m0 = (wv >> 1) * 32;
    const int n0 = (wv & 1) * 32;
    f32x4 acc[2][2];
#pragma unroll
    for (int a = 0; a < 2; a++)
#pragma unroll
        for (int b = 0; b < 2; b++) acc[a][b] = (f32x4){0.f, 0.f, 0.f, 0.f};

#pragma unroll
    for (int ks = 0; ks < 8; ks++) {
        int ko = ks * 32 + lg * 8;
        bf16x8 a0 = *(const bf16x8*)&A_lds[(m0 + lr) * 264 + ko];
        bf16x8 a1 = *(const bf16x8*)&A_lds[(m0 + 16 + lr) * 264 + ko];
        bf16x8 b0 = *(const bf16x8*)&B_lds[(n0 + lr) * 264 + ko];
        bf16x8 b1 = *(const bf16x8*)&B_lds[(n0 + 16 + lr) * 264 + ko];
        acc[0][0] = __builtin_amdgcn_mfma_f32_16x16x32_bf16(a0, b0, acc[0][0], 0, 0, 0);
        acc[0][1] = __builtin_amdgcn_mfma_f32_16x16x32_bf16(a0, b1, acc[0][1], 0, 0, 0);
        acc[1][0] = __builtin_amdgcn_mfma_f32_16x16x32_bf16(a1, b0, acc[1][0], 0, 0, 0);
        acc[1][1] = __builtin_amdgcn_mfma_f32_16x16x32_bf16(a1, b1, acc[1][1], 0, 0, 0);
    }

    const bool isL = (n0 == 0);
    const float scale = isL ? 0.0078125f : 1.f;
#pragma unroll
    for (int mt = 0; mt < 2; mt++)
#pragma unroll
        for (int nt = 0; nt < 2; nt++) {
            int ch = (n0 + nt * 16 + lr) & 31;
            float bias = isL ? bl[ch] : br[ch];
            us4 pk;
#pragma unroll
            for (int rg = 0; rg < 4; rg++)
                pk[rg] = f2bf((acc[mt][nt][rg] + bias) * scale);
            unsigned short* dst = (isL ? Lt : Rt) + (size_t)(i * CH + ch) * SS
                                  + sh * 64 + m0 + mt * 16 + lg * 4;
            *(us4*)dst = pk;
        }
}

// ---------------- K2: fused GEMM1 (outer) + GEMM2 (@Wo), PERSISTENT ----------------
// Grid = 256 blocks (1/CU), each owns 9 consecutive tiles (tid = b*9+t, i-major
// order so consecutive tiles usually share the A panel -> L2 reuse).
// Cross-tile pipeline: tile t+1's A/B fetched global->regs during tile t's
// phase 2 (~5000 cyc of MFMA covers the L2/L3 fetch), committed to LDS after
// the reduction frees it. Staging exposure ~2400cyc -> ~LDS-write cost only.
//
// LDS plan (139264 bytes):
//   phase 1 : A [0,65536)  B [65536,131072)
//             XOR-plane layout: element (row,k) -> plane(k>>6)*32KB
//             + row*64 + ((((k>>3)&7) ^ (row&7))*8 + (k&7))  [shorts]
//   phase 2 : Oh0 [0,65536)  Oh1 [65536,131072)  (Wo direct from L2 via WoF)
//   reduce  : RB f32 [0,139264)
#define TI 8
#define TJ 8
#define TPB 9          // tiles per persistent block; 256*9 = 2304 = 48*48
#define P1_B_OFF 65536
#define OH1_OFF  65536
#define K2_LDS   139264

// fragment read: o = k-octet index 0..15
#define FRAG(base, row, o) \
    (*(const bf16x8*)((base) + (((o) & 8) << 11) + (row) * 64 + ((((o) & 7) ^ ((row) & 7)) << 3)))

__global__ __launch_bounds__(512, 2) void k2_fused(
    const unsigned short* __restrict__ Lt, const unsigned short* __restrict__ Rt,
    const unsigned short* __restrict__ WoF, const float* __restrict__ bo,
    float* __restrict__ out)
{
    extern __shared__ char smem[];
    unsigned short* A = (unsigned short*)(smem);             // planes [2][256][64]
    unsigned short* B = (unsigned short*)(smem + P1_B_OFF);  // planes [2][256][64]

    const int t  = threadIdx.x;
    const int wv = t >> 6, lane = t & 63;
    const int lr = lane & 15, lg = lane >> 4;
    const int zsl = wv & 1, ksl = wv >> 1;
    const int m0  = (wv >> 2) * 128;
    const int n0w = (wv & 3) * 64;

    // per-thread staging geometry (constant across tiles): u-th chunk covers
    // octet c = u*512+t : row = c>>4, kc = c&15
    int srow[8], skc[8], sdst[8];
#pragma unroll
    for (int u = 0; u < 8; u++) {
        int c = u * 512 + t;
        srow[u] = c >> 4;
        skc[u]  = c & 15;
        sdst[u] = (skc[u] >> 3) * 16384 + srow[u] * 64 + ((skc[u] & 7) ^ (srow[u] & 7)) * 8;
    }

    us8 rA[8], rB[8];
    int tid = blockIdx.x * TPB;

    // ---- prologue: stage tile 0 ----
    {
        const unsigned short* gA = Lt + (size_t)((tid / 48) * TI) * CH * SS;
        const unsigned short* gB = Rt + (size_t)((tid % 48) * TJ) * CH * SS;
#pragma unroll
        for (int u = 0; u < 8; u++) {
            rA[u] = *(const us8*)(gA + srow[u] * 128 + skc[u] * 8);
            rB[u] = *(const us8*)(gB + srow[u] * 128 + skc[u] * 8);
        }
#pragma unroll
        for (int u = 0; u < 8; u++) {
            *(us8*)(A + sdst[u]) = rA[u];
            *(us8*)(B + sdst[u]) = rB[u];
        }
    }
    __syncthreads();

    for (int tt = 0; tt < TPB; tt++, tid++) {
        const int i0 = (tid / 48) * TI;
        const int j0 = (tid % 48) * TJ;

        // ---- Phase 1 compute: 256x256x128, wave tile 128x64, operands swapped ----
        f32x4 accE[4][4], accO[4][4];
#pragma unroll
        for (int a = 0; a < 4; a++)
#pragma unroll
            for (int b = 0; b < 4; b++) {
                accE[a][b] = (f32x4){0.f, 0.f, 0.f, 0.f};
                accO[a][b] = (f32x4){0.f, 0.f, 0.f, 0.f};
            }

#pragma unroll
        for (int ks = 0; ks < 4; ks++) {
            int o = ks * 4 + lg;
            bf16x8 af[8], bfr[4];
#pragma unroll
            for (int mt = 0; mt < 8; mt++) af[mt]  = FRAG(A, m0 + mt * 16 + lr, o);
#pragma unroll
            for (int nt = 0; nt < 4; nt++) bfr[nt] = FRAG(B, n0w + nt * 16 + lr, o);
#pragma unroll
            for (int mt = 0; mt < 8; mt++)
#pragma unroll
                for (int nt = 0; nt < 4; nt++) {
                    if (mt & 1)
                        accO[mt >> 1][nt] = __builtin_amdgcn_mfma_f32_16x16x32_bf16(bfr[nt], af[mt], accO[mt >> 1][nt], 0, 0, 0);
                    else
                        accE[mt >> 1][nt] = __builtin_amdgcn_mfma_f32_16x16x32_bf16(bfr[nt], af[mt], accE[mt >> 1][nt], 0, 0, 0);
                }
        }

        // ---- 2-deep Wo prefetch (chunks 0,1); latency hidden behind dump ----
        bf16x8 wbuf[2][4];
#pragma unroll
        for (int bi = 0; bi < 4; bi++)
            wbuf[0][bi] = *(const bf16x8*)&WoF[(((size_t)(0 * 4 + ksl) * 8 + zsl * 4 + bi) * 64 + lane) * 8];
#pragma unroll
        for (int bi = 0; bi < 4; bi++)
            wbuf[1][bi] = *(const bf16x8*)&WoF[(((size_t)(1 * 4 + ksl) * 8 + zsl * 4 + bi) * 64 + lane) * 8];

        __syncthreads();   // phase-1 A/B LDS reads done; LDS repurposed to Oh

        // ---- Dump BOTH O halves with b64 packed writes ----
        {
            unsigned short* Oh0 = (unsigned short*)smem;
            unsigned short* Oh1 = (unsigned short*)(smem + OH1_OFF);
#pragma unroll
            for (int mh = 0; mh < 4; mh++) {
                int iiw  = (wv >> 2) * 4 + mh;
                int rowH = iiw * 16 + lr;
                int okey = (rowH ^ (rowH >> 4)) & 7;
#pragma unroll
                for (int nt = 0; nt < 4; nt++) {
                    int colBase = n0w + nt * 16 + lg * 4;
                    int chk = (colBase >> 3) ^ okey;
                    int off = rowH * 256 + chk * 8 + (lg & 1) * 4;
                    us4 pkE, pkO;
#pragma unroll
                    for (int rg = 0; rg < 4; rg++) {
                        pkE[rg] = f2bf(accE[mh][nt][rg]);
                        pkO[rg] = f2bf(accO[mh][nt][rg]);
                    }
                    *(us4*)&Oh0[off] = pkE;
                    *(us4*)&Oh1[off] = pkO;
                }
            }
        }
        __syncthreads();   // O dump visible to all waves

        // ---- issue next tile's A/B fetch; drains during phase 2 ----
        if (tt < TPB - 1) {
            int ntid = tid + 1;
            const unsigned short* gA = Lt + (size_t)((ntid / 48) * TI) * CH * SS;
            const unsigned short* gB = Rt + (size_t)((ntid % 48) * TJ) * CH * SS;
#pragma unroll
            for (int u = 0; u < 8; u++) {
                rA[u] = *(const us8*)(gA + srow[u] * 128 + skc[u] * 8);
                rB[u] = *(const us8*)(gB + srow[u] * 128 + skc[u] * 8);
            }
        }

        // ---- Phase 2: out[pair=64][z=128] = O[64][1024] @ WoF, barrier-free ----
        f32x4 acc2[4][4];
#pragma unroll
        for (int a = 0; a < 4; a++)
#pragma unroll
            for (int b = 0; b < 4; b++) acc2[a][b] = (f32x4){0.f, 0.f, 0.f, 0.f};

#pragma unroll
        for (int c = 0; c < 8; c++) {
            const int cch = c * 4 + ksl;           // 0..31
            const int hh  = cch >> 4;
            const int cH  = cch & 15;
            const unsigned short* OhX = (const unsigned short*)(smem + (hh ? OH1_OFF : 0));

            bf16x8 af2[4];
#pragma unroll
            for (int ai = 0; ai < 4; ai++) {
                int rowH = (ai * 2 + ((lane >> 3) & 1)) * 16 + cH;
                int okey = (rowH ^ (rowH >> 4)) & 7;
                int chk  = (((lane & 7) * 4 + lg) ^ okey);
                af2[ai] = *(const bf16x8*)&OhX[rowH * 256 + chk * 8];
            }
#pragma unroll
            for (int ai = 0; ai < 4; ai++)
#pragma unroll
                for (int bi = 0; bi < 4; bi++)
                    acc2[ai][bi] = __builtin_amdgcn_mfma_f32_16x16x32_bf16(af2[ai], wbuf[c & 1][bi], acc2[ai][bi], 0, 0, 0);

            if (c < 6) {   // refill consumed slot with chunk c+2
                int cchn = (c + 2) * 4 + ksl;
#pragma unroll
                for (int bi = 0; bi < 4; bi++)
                    wbuf[c & 1][bi] = *(const bf16x8*)&WoF[(((size_t)cchn * 8 + zsl * 4 + bi) * 64 + lane) * 8];
            }
        }
        __syncthreads();   // O reads done; LDS -> reduction buffer

        // ---- K-slot reduction: RB[4 ks][128 z][68 pair-stride] f32 ----
        float* RB = (float*)smem;
#pragma unroll
        for (int ai = 0; ai < 4; ai++)
#pragma unroll
            for (int bi = 0; bi < 4; bi++) {
                int z  = zsl * 64 + bi * 16 + lr;
                int pr = ai * 16 + lg * 4;
                *(f32x4*)&RB[ksl * 8704 + z * 68 + pr] = acc2[ai][bi];
            }
        __syncthreads();

        {
            int z = t >> 2, pq = t & 3;
            float bz = bo[z];
#pragma unroll
            for (int u = 0; u < 4; u++) {
                int p0r = pq * 16 + u * 4;
                f32x4 s = (f32x4){0.f, 0.f, 0.f, 0.f};
#pragma unroll
                for (int ks2 = 0; ks2 < 4; ks2++)
                    s += *(const f32x4*)&RB[ks2 * 8704 + z * 68 + p0r];
#pragma unroll
                for (int e = 0; e < 4; e++) {
                    int p = p0r + e;
                    out[((size_t)(i0 + (p >> 3)) * NN + (j0 + (p & 7))) * CZ + z] = s[e] + bz;
                }
            }
        }
        __syncthreads();   // RB reads done; LDS free for next tile's A/B

        // ---- commit next tile's A/B from regs to LDS ----
        if (tt < TPB - 1) {
#pragma unroll
            for (int u = 0; u < 8; u++) {
                *(us8*)(A + sdst[u]) = rA[u];
                *(us8*)(B + sdst[u]) = rB[u];
            }
        }
        __syncthreads();   // staging visible before next phase 1
    }
}

extern "C" void kernel_launch(void* const* d_in, const int* in_sizes, int n_in,
                              void* d_out, int out_size, void* d_ws, size_t ws_size,
                              hipStream_t stream) {
    const float* msa  = (const float*)d_in[0];
    const float* ln_g = (const float*)d_in[1];
    const float* ln_b = (const float*)d_in[2];
    const float* Wl   = (const float*)d_in[3];
    const float* bl   = (const float*)d_in[4];
    const float* Wr   = (const float*)d_in[5];
    const float* br   = (const float*)d_in[6];
    const float* Wo   = (const float*)d_in[7];
    const float* bo   = (const float*)d_in[8];
    float* out = (float*)d_out;

    unsigned short* Lt  = (unsigned short*)d_ws;                 // [12288][128] bf16
    unsigned short* Rt  = Lt + (size_t)NN * CH * SS;             // [12288][128] bf16
    unsigned short* WoF = Rt + (size_t)NN * CH * SS;             // [32][8][64][8] bf16 fragment-linear
    unsigned short* WT  = WoF + (size_t)CZ * CH * CH;            // [64][256] bf16 (WlT|WrT)

    hipFuncSetAttribute((const void*)k2_fused,
                        hipFuncAttributeMaxDynamicSharedMemorySize, K2_LDS);

    k0_transpose<<<dim3(CZ), dim3(256), 0, stream>>>(Wo, Wl, Wr, WoF, WT);
    k1_ln_proj<<<dim3(NN, 2), dim3(256), 0, stream>>>(msa, ln_g, ln_b, WT, bl, br, Lt, Rt);
    k2_fused<<<dim3(256), dim3(512), K2_LDS, stream>>>(Lt, Rt, WoF, bo, out);
}

// Round 4
// 210.120 us; speedup vs baseline: 2.2471x; 2.2471x over previous
//
#include <hip/hip_runtime.h>
#include <hip/hip_bf16.h>

#define CM 256
#define CZ 128
#define CH 32
#define SS 128
#define NN 384

typedef short bf16x8 __attribute__((ext_vector_type(8)));
typedef float f32x4 __attribute__((ext_vector_type(4)));
typedef unsigned short us4 __attribute__((ext_vector_type(4)));
typedef unsigned short us8 __attribute__((ext_vector_type(8)));

__device__ __forceinline__ unsigned short f2bf(float f) {
    __hip_bfloat16 h = __float2bfloat16(f);
    return __builtin_bit_cast(unsigned short, h);
}

// ---------------- K0: weight prep ----------------
// WoF: fragment-linear Wo for k2 phase-2 direct loads:
//   WoF[(((cch*8)+zb)*64 + l)*8 + e] = Wo[(cch*32 + (l>>4)*8 + e)][zb*16 + (l&15)]
// WT = [WlT(32x256) | WrT(32x256)]
__global__ __launch_bounds__(256) void k0_transpose(
    const float* __restrict__ Wo, const float* __restrict__ Wl, const float* __restrict__ Wr,
    unsigned short* __restrict__ WoF, unsigned short* __restrict__ WT) {
    int n = blockIdx.x;  // 0..127
    int base = n * 1024;
#pragma unroll
    for (int u = 0; u < 4; u++) {
        int w   = base + u * 256 + threadIdx.x;   // 0..131071
        int e   = w & 7;
        int l   = (w >> 3) & 63;
        int zb  = (w >> 9) & 7;
        int cch = w >> 12;
        WoF[w] = f2bf(Wo[(size_t)(cch * 32 + (l >> 4) * 8 + e) * CZ + zb * 16 + (l & 15)]);
    }
    int k = threadIdx.x;  // blockDim == 256 == CM
    if (n < 32) {
        WT[n * CM + k] = f2bf(Wl[(size_t)k * CH + n]);
    } else if (n < 64) {
        WT[32 * CM + (n - 32) * CM + k] = f2bf(Wr[(size_t)k * CH + (n - 32)]);
    }
}

// ---------------- K1: LayerNorm + projections. Block = (i, s-half of 64). 256 thr, 2 blocks/CU ----------------
// unroll 8 on the row loop: 8 strided 1KB loads in flight -> latency-hiding
// (round-3 evidence: k1 ~100us -> ~30us from this alone)
__global__ __launch_bounds__(256, 2) void k1_ln_proj(
    const float* __restrict__ msa, const float* __restrict__ g, const float* __restrict__ bta,
    const unsigned short* __restrict__ WT, const float* __restrict__ bl, const float* __restrict__ br,
    unsigned short* __restrict__ Lt, unsigned short* __restrict__ Rt)
{
    __shared__ unsigned short A_lds[64 * 264];
    __shared__ unsigned short B_lds[64 * 264];

    const int i    = blockIdx.x;
    const int sh   = blockIdx.y;
    const int t    = threadIdx.x;
    const int wv   = t >> 6;
    const int lane = t & 63;
    const int lr   = lane & 15, lg = lane >> 4;

    const float4 gv = ((const float4*)g)[lane];
    const float4 bv = ((const float4*)bta)[lane];
#pragma unroll 8
    for (int r = 0; r < 16; r++) {
        int sl = wv * 16 + r;
        int s  = sh * 64 + sl;
        float4 v = ((const float4*)(msa + ((size_t)s * NN + i) * CM))[lane];
        float sum = v.x + v.y + v.z + v.w;
        float sq  = v.x * v.x + v.y * v.y + v.z * v.z + v.w * v.w;
#pragma unroll
        for (int off = 32; off >= 1; off >>= 1) {
            sum += __shfl_xor(sum, off, 64);
            sq  += __shfl_xor(sq, off, 64);
        }
        float mu = sum * (1.f / CM);
        float rs = rsqrtf(sq * (1.f / CM) - mu * mu + 1e-5f);
        us4 pk;
        pk[0] = f2bf((v.x - mu) * rs * gv.x + bv.x);
        pk[1] = f2bf((v.y - mu) * rs * gv.y + bv.y);
        pk[2] = f2bf((v.z - mu) * rs * gv.z + bv.z);
        pk[3] = f2bf((v.w - mu) * rs * gv.w + bv.w);
        *(us4*)&A_lds[sl * 264 + lane * 4] = pk;
    }
#pragma unroll
    for (int u = 0; u < 8; u++) {
        int id = u * 256 + t;
        *(us8*)&B_lds[(id >> 5) * 264 + (id & 31) * 8] = *(const us8*)&WT[id * 8];
    }
    __syncthreads();

    const int m0 = (wv >> 1) * 32;
    const int n0 = (wv & 1) * 32;
    f32x4 acc[2][2];
#pragma unroll
    for (int a = 0; a < 2; a++)
#pragma unroll
        for (int b = 0; b < 2; b++) acc[a][b] = (f32x4){0.f, 0.f, 0.f, 0.f};

#pragma unroll
    for (int ks = 0; ks < 8; ks++) {
        int ko = ks * 32 + lg * 8;
        bf16x8 a0 = *(const bf16x8*)&A_lds[(m0 + lr) * 264 + ko];
        bf16x8 a1 = *(const bf16x8*)&A_lds[(m0 + 16 + lr) * 264 + ko];
        bf16x8 b0 = *(const bf16x8*)&B_lds[(n0 + lr) * 264 + ko];
        bf16x8 b1 = *(const bf16x8*)&B_lds[(n0 + 16 + lr) * 264 + ko];
        acc[0][0] = __builtin_amdgcn_mfma_f32_16x16x32_bf16(a0, b0, acc[0][0], 0, 0, 0);
        acc[0][1] = __builtin_amdgcn_mfma_f32_16x16x32_bf16(a0, b1, acc[0][1], 0, 0, 0);
        acc[1][0] = __builtin_amdgcn_mfma_f32_16x16x32_bf16(a1, b0, acc[1][0], 0, 0, 0);
        acc[1][1] = __builtin_amdgcn_mfma_f32_16x16x32_bf16(a1, b1, acc[1][1], 0, 0, 0);
    }

    const bool isL = (n0 == 0);
    const float scale = isL ? 0.0078125f : 1.f;
#pragma unroll
    for (int mt = 0; mt < 2; mt++)
#pragma unroll
        for (int nt = 0; nt < 2; nt++) {
            int ch = (n0 + nt * 16 + lr) & 31;
            float bias = isL ? bl[ch] : br[ch];
            us4 pk;
#pragma unroll
            for (int rg = 0; rg < 4; rg++)
                pk[rg] = f2bf((acc[mt][nt][rg] + bias) * scale);
            unsigned short* dst = (isL ? Lt : Rt) + (size_t)(i * CH + ch) * SS
                                  + sh * 64 + m0 + mt * 16 + lg * 4;
            *(us4*)dst = pk;
        }
}

// ---------------- K2: fused GEMM1 (outer) + GEMM2 (@Wo) ----------------
// Round-1 structure (grid 48x48 -- L2 locality preserved) + XOR-plane A/B
// layout (round-2 measured: conflicts 8.26M -> 4.72M) staged via coalesced
// ds_write from registers (NOT global_load_lds source-permute).
//
// LDS plan (139264 bytes):
//   phase 1 : A [0,65536)  B [65536,131072)
//             XOR-plane layout: element (row,k) -> plane(k>>6)*32KB
//             + row*64 + ((((k>>3)&7) ^ (row&7))*8 + (k&7))  [shorts]
//   phase 2 : Oh0 [0,65536)  Oh1 [65536,131072)  (Wo direct from L2 via WoF)
//   reduce  : RB f32 [0,139264)
#define TI 8
#define TJ 8
#define P1_B_OFF 65536
#define OH1_OFF  65536
#define K2_LDS   139264

// fragment read: o = k-octet index 0..15
#define FRAG(base, row, o) \
    (*(const bf16x8*)((base) + (((o) & 8) << 11) + (row) * 64 + ((((o) & 7) ^ ((row) & 7)) << 3)))

__global__ __launch_bounds__(512, 2) void k2_fused(
    const unsigned short* __restrict__ Lt, const unsigned short* __restrict__ Rt,
    const unsigned short* __restrict__ WoF, const float* __restrict__ bo,
    float* __restrict__ out)
{
    extern __shared__ char smem[];
    unsigned short* A = (unsigned short*)(smem);             // planes [2][256][64]
    unsigned short* B = (unsigned short*)(smem + P1_B_OFF);  // planes [2][256][64]

    const int i0 = blockIdx.x * TI;
    const int j0 = blockIdx.y * TJ;
    const int t  = threadIdx.x;
    const int wv = t >> 6, lane = t & 63;
    const int lr = lane & 15, lg = lane >> 4;

    // ---- Phase 1 staging: coalesced global read -> reg -> XOR-plane ds_write ----
    // chunk c = u*512+t : row = c>>4, octet kc = c&15 ; global [row][kc*8] (contig)
    // LDS dst = plane(kc>>3) + row*64 + ((kc&7)^(row&7))*8 : per 16-lane phase the
    // 16 b128 writes cover two full 128B bank-sweeps -> conflict-free.
    const unsigned short* gA = Lt + (size_t)i0 * CH * SS;
    const unsigned short* gB = Rt + (size_t)j0 * CH * SS;
#pragma unroll
    for (int u = 0; u < 8; u++) {
        int c   = u * 512 + t;
        int row = c >> 4, kc = c & 15;
        int dst = (kc >> 3) * 16384 + row * 64 + ((kc & 7) ^ (row & 7)) * 8;
        *(us8*)(A + dst) = *(const us8*)(gA + row * 128 + kc * 8);
        *(us8*)(B + dst) = *(const us8*)(gB + row * 128 + kc * 8);
    }
    __syncthreads();

    // ---- Phase 1 compute: 256x256x128, wave tile 128x64, operands swapped ----
    const int m0  = (wv >> 2) * 128;
    const int n0w = (wv & 3) * 64;

    f32x4 accE[4][4], accO[4][4];
#pragma unroll
    for (int a = 0; a < 4; a++)
#pragma unroll
        for (int b = 0; b < 4; b++) {
            accE[a][b] = (f32x4){0.f, 0.f, 0.f, 0.f};
            accO[a][b] = (f32x4){0.f, 0.f, 0.f, 0.f};
        }

#pragma unroll
    for (int ks = 0; ks < 4; ks++) {
        int o = ks * 4 + lg;
        bf16x8 af[8], bfr[4];
#pragma unroll
        for (int mt = 0; mt < 8; mt++) af[mt]  = FRAG(A, m0 + mt * 16 + lr, o);
#pragma unroll
        for (int nt = 0; nt < 4; nt++) bfr[nt] = FRAG(B, n0w + nt * 16 + lr, o);
#pragma unroll
        for (int mt = 0; mt < 8; mt++)
#pragma unroll
            for (int nt = 0; nt < 4; nt++) {
                if (mt & 1)
                    accO[mt >> 1][nt] = __builtin_amdgcn_mfma_f32_16x16x32_bf16(bfr[nt], af[mt], accO[mt >> 1][nt], 0, 0, 0);
                else
                    accE[mt >> 1][nt] = __builtin_amdgcn_mfma_f32_16x16x32_bf16(bfr[nt], af[mt], accE[mt >> 1][nt], 0, 0, 0);
            }
    }

    // ---- Wave role for phase 2 ----
    const int zsl = wv & 1, ksl = wv >> 1;

    // ---- 2-deep Wo prefetch (chunks 0,1) straight from L2; latency hidden behind dump ----
    bf16x8 wbuf[2][4];
#pragma unroll
    for (int bi = 0; bi < 4; bi++)
        wbuf[0][bi] = *(const bf16x8*)&WoF[(((size_t)(0 * 4 + ksl) * 8 + zsl * 4 + bi) * 64 + lane) * 8];
#pragma unroll
    for (int bi = 0; bi < 4; bi++)
        wbuf[1][bi] = *(const bf16x8*)&WoF[(((size_t)(1 * 4 + ksl) * 8 + zsl * 4 + bi) * 64 + lane) * 8];

    __syncthreads();   // phase-1 A/B LDS reads done; LDS repurposed to Oh

    // ---- Dump BOTH O halves with b64 packed writes ----
    {
        unsigned short* Oh0 = (unsigned short*)smem;
        unsigned short* Oh1 = (unsigned short*)(smem + OH1_OFF);
#pragma unroll
        for (int mh = 0; mh < 4; mh++) {
            int iiw  = (wv >> 2) * 4 + mh;
            int rowH = iiw * 16 + lr;
            int okey = (rowH ^ (rowH >> 4)) & 7;
#pragma unroll
            for (int nt = 0; nt < 4; nt++) {
                int colBase = n0w + nt * 16 + lg * 4;
                int chk = (colBase >> 3) ^ okey;
                int off = rowH * 256 + chk * 8 + (lg & 1) * 4;
                us4 pkE, pkO;
#pragma unroll
                for (int rg = 0; rg < 4; rg++) {
                    pkE[rg] = f2bf(accE[mh][nt][rg]);
                    pkO[rg] = f2bf(accO[mh][nt][rg]);
                }
                *(us4*)&Oh0[off] = pkE;
                *(us4*)&Oh1[off] = pkO;
            }
        }
    }
    __syncthreads();   // O dump visible to all waves

    // ---- Phase 2: out[pair=64][z=128] = O[64][1024] @ WoF, barrier-free, 2-deep pipeline ----
    f32x4 acc2[4][4];
#pragma unroll
    for (int a = 0; a < 4; a++)
#pragma unroll
        for (int b = 0; b < 4; b++) acc2[a][b] = (f32x4){0.f, 0.f, 0.f, 0.f};

#pragma unroll
    for (int c = 0; c < 8; c++) {
        const int cch = c * 4 + ksl;           // 0..31
        const int hh  = cch >> 4;
        const int cH  = cch & 15;
        const unsigned short* OhX = (const unsigned short*)(smem + (hh ? OH1_OFF : 0));

        bf16x8 af2[4];
#pragma unroll
        for (int ai = 0; ai < 4; ai++) {
            int rowH = (ai * 2 + ((lane >> 3) & 1)) * 16 + cH;
            int okey = (rowH ^ (rowH >> 4)) & 7;
            int chk  = (((lane & 7) * 4 + lg) ^ okey);
            af2[ai] = *(const bf16x8*)&OhX[rowH * 256 + chk * 8];
        }
#pragma unroll
        for (int ai = 0; ai < 4; ai++)
#pragma unroll
            for (int bi = 0; bi < 4; bi++)
                acc2[ai][bi] = __builtin_amdgcn_mfma_f32_16x16x32_bf16(af2[ai], wbuf[c & 1][bi], acc2[ai][bi], 0, 0, 0);

        if (c < 6) {   // refill consumed slot with chunk c+2
            int cchn = (c + 2) * 4 + ksl;
#pragma unroll
            for (int bi = 0; bi < 4; bi++)
                wbuf[c & 1][bi] = *(const bf16x8*)&WoF[(((size_t)cchn * 8 + zsl * 4 + bi) * 64 + lane) * 8];
        }
    }
    __syncthreads();   // O reads done; LDS -> reduction buffer

    // ---- K-slot reduction: RB[4 ks][128 z][68 pair-stride] f32 ----
    float* RB = (float*)smem;
#pragma unroll
    for (int ai = 0; ai < 4; ai++)
#pragma unroll
        for (int bi = 0; bi < 4; bi++) {
            int z  = zsl * 64 + bi * 16 + lr;
            int pr = ai * 16 + lg * 4;
            *(f32x4*)&RB[ksl * 8704 + z * 68 + pr] = acc2[ai][bi];
        }
    __syncthreads();

    {
        int z = t >> 2, pq = t & 3;
        float bz = bo[z];
#pragma unroll
        for (int u = 0; u < 4; u++) {
            int p0r = pq * 16 + u * 4;
            f32x4 s = (f32x4){0.f, 0.f, 0.f, 0.f};
#pragma unroll
            for (int ks2 = 0; ks2 < 4; ks2++)
                s += *(const f32x4*)&RB[ks2 * 8704 + z * 68 + p0r];
#pragma unroll
            for (int e = 0; e < 4; e++) {
                int p = p0r + e;
                out[((size_t)(i0 + (p >> 3)) * NN + (j0 + (p & 7))) * CZ + z] = s[e] + bz;
            }
        }
    }
}

extern "C" void kernel_launch(void* const* d_in, const int* in_sizes, int n_in,
                              void* d_out, int out_size, void* d_ws, size_t ws_size,
                              hipStream_t stream) {
    const float* msa  = (const float*)d_in[0];
    const float* ln_g = (const float*)d_in[1];
    const float* ln_b = (const float*)d_in[2];
    const float* Wl   = (const float*)d_in[3];
    const float* bl   = (const float*)d_in[4];
    const float* Wr   = (const float*)d_in[5];
    const float* br   = (const float*)d_in[6];
    const float* Wo   = (const float*)d_in[7];
    const float* bo   = (const float*)d_in[8];
    float* out = (float*)d_out;

    unsigned short* Lt  = (unsigned short*)d_ws;                 // [12288][128] bf16
    unsigned short* Rt  = Lt + (size_t)NN * CH * SS;             // [12288][128] bf16
    unsigned short* WoF = Rt + (size_t)NN * CH * SS;             // [32][8][64][8] bf16 fragment-linear
    unsigned short* WT  = WoF + (size_t)CZ * CH * CH;            // [64][256] bf16 (WlT|WrT)

    hipFuncSetAttribute((const void*)k2_fused,
                        hipFuncAttributeMaxDynamicSharedMemorySize, K2_LDS);

    k0_transpose<<<dim3(CZ), dim3(256), 0, stream>>>(Wo, Wl, Wr, WoF, WT);
    k1_ln_proj<<<dim3(NN, 2), dim3(256), 0, stream>>>(msa, ln_g, ln_b, WT, bl, br, Lt, Rt);
    k2_fused<<<dim3(NN / TI, NN / TJ), dim3(512), K2_LDS, stream>>>(Lt, Rt, WoF, bo, out);
}